// Round 4
// baseline (413.744 us; speedup 1.0000x reference)
//
#include <hip/hip_runtime.h>
#include <hip/hip_bf16.h>

// GAT-style graph attention. N=50000, E=600000, FEAT=128, H=8, D=16.
// R4: dual CSR (src + dest). Scores: one wave per src node, Q in regs,
//     shfl-reduce per-head dots, in-register segsum (no atomics/recip).
//     Gather: streaming src_sorted + prenormalized wnorm, 4x-unrolled
//     random V loads for MLP. bf16 MFMA GEMMs from R3.

#define FEAT 128
#define NHEAD 8
#define NPAD 50048   // N rounded up to multiple of 64

typedef __attribute__((ext_vector_type(8))) short bf16x8;
typedef __attribute__((ext_vector_type(4))) float f32x4;

__device__ __forceinline__ unsigned short f2bf(float f) {
    unsigned u = __float_as_uint(f);
    u += 0x7fffu + ((u >> 16) & 1u);
    return (unsigned short)(u >> 16);
}
__device__ __forceinline__ float bf2f_lo(unsigned u) { return __uint_as_float(u << 16); }
__device__ __forceinline__ float bf2f_hi(unsigned u) { return __uint_as_float(u & 0xffff0000u); }

// ---- convert X to bf16, 8 elems/thread ----
__global__ __launch_bounds__(256) void convert_x_kernel(
    const float* __restrict__ X, unsigned short* __restrict__ Xb, int total8)
{
    int i = blockIdx.x * 256 + threadIdx.x;
    if (i >= total8) return;
    const float4* xp = (const float4*)X + (size_t)i * 2;
    float4 x0 = xp[0], x1 = xp[1];
    uint4 o;
    o.x = (unsigned)f2bf(x0.x) | ((unsigned)f2bf(x0.y) << 16);
    o.y = (unsigned)f2bf(x0.z) | ((unsigned)f2bf(x0.w) << 16);
    o.z = (unsigned)f2bf(x1.x) | ((unsigned)f2bf(x1.y) << 16);
    o.w = (unsigned)f2bf(x1.z) | ((unsigned)f2bf(x1.w) << 16);
    ((uint4*)Xb)[i] = o;
}

// ---- convert 4 weight matrices to bf16 ----
__global__ __launch_bounds__(256) void convert_w_kernel(
    const float* __restrict__ Wq, const float* __restrict__ Wk,
    const float* __restrict__ Wv, const float* __restrict__ Wo,
    unsigned short* __restrict__ Wb)
{
    int i = blockIdx.x * 256 + threadIdx.x;
    if (i >= 4 * 2048) return;
    int mat = i >> 11, idx = i & 2047;
    const float* W = (mat == 0) ? Wq : (mat == 1) ? Wk : (mat == 2) ? Wv : Wo;
    const float4* xp = (const float4*)W + (size_t)idx * 2;
    float4 x0 = xp[0], x1 = xp[1];
    uint4 o;
    o.x = (unsigned)f2bf(x0.x) | ((unsigned)f2bf(x0.y) << 16);
    o.y = (unsigned)f2bf(x0.z) | ((unsigned)f2bf(x0.w) << 16);
    o.z = (unsigned)f2bf(x1.x) | ((unsigned)f2bf(x1.y) << 16);
    o.w = (unsigned)f2bf(x1.z) | ((unsigned)f2bf(x1.w) << 16);
    ((uint4*)(Wb + (size_t)mat * 16384))[idx] = o;
}

// ---- combined histogram: counts[s] and counts[N+d] ----
__global__ __launch_bounds__(256) void hist2_kernel(
    const int* __restrict__ srcs, const int* __restrict__ dsts,
    int* __restrict__ counts, int N, int E)
{
    int e = blockIdx.x * 256 + threadIdx.x;
    if (e < E) {
        atomicAdd(counts + srcs[e], 1);
        atomicAdd(counts + N + dsts[e], 1);
    }
}

// ---- scan over concatenated [src counts | dest counts] (2N elems) ----
__global__ __launch_bounds__(256) void scan1_kernel(
    const int* __restrict__ counts, int* __restrict__ offsets,
    int* __restrict__ blocksums, int NT)
{
    __shared__ int buf[256];
    int t = threadIdx.x, i = blockIdx.x * 256 + t;
    int v = (i < NT) ? counts[i] : 0;
    buf[t] = v; __syncthreads();
    int x = v;
    #pragma unroll
    for (int off = 1; off < 256; off <<= 1) {
        int y = (t >= off) ? buf[t - off] : 0;
        __syncthreads();
        x += y; buf[t] = x;
        __syncthreads();
    }
    if (i < NT) offsets[i] = x - v;
    if (t == 255) blocksums[blockIdx.x] = x;
}

__global__ __launch_bounds__(512) void scan2_kernel(
    int* __restrict__ blocksums, int* __restrict__ blockoffs, int NB)
{
    __shared__ int buf[512];
    int t = threadIdx.x;
    int v = (t < NB) ? blocksums[t] : 0;
    buf[t] = v; __syncthreads();
    int x = v;
    #pragma unroll
    for (int off = 1; off < 512; off <<= 1) {
        int y = (t >= off) ? buf[t - off] : 0;
        __syncthreads();
        x += y; buf[t] = x;
        __syncthreads();
    }
    if (t < NB) blockoffs[t] = x - v;
}

__global__ __launch_bounds__(256) void scan3_kernel(
    int* __restrict__ offsets, const int* __restrict__ blockoffs,
    int* __restrict__ cursor, int NT)
{
    int i = blockIdx.x * 256 + threadIdx.x;
    if (i < NT) {
        int o = offsets[i] + blockoffs[blockIdx.x];
        offsets[i] = o;
        cursor[i] = o;
    }
}

// ---- fill src-CSR: original edge id + dest node, in src-sorted order ----
__global__ __launch_bounds__(256) void fill_src_kernel(
    const int* __restrict__ srcs, const int* __restrict__ dsts,
    int* __restrict__ cursor, int* __restrict__ eid_src,
    int* __restrict__ dst_sorted, int E)
{
    int e = blockIdx.x * 256 + threadIdx.x;
    if (e < E) {
        int s = srcs[e];
        int pos = atomicAdd(cursor + s, 1);
        eid_src[pos] = e;
        dst_sorted[pos] = dsts[e];
    }
}

// ---- QKV MFMA GEMM: 64 rows/block, wave=16 rows, 3 matrices ----
__global__ __launch_bounds__(256) void qkv_mfma_kernel(
    const unsigned short* __restrict__ Xb, const unsigned short* __restrict__ Wb,
    const float* __restrict__ bq, const float* __restrict__ bk, const float* __restrict__ bv,
    unsigned short* __restrict__ Q, unsigned short* __restrict__ K,
    unsigned short* __restrict__ V, int N)
{
    const int lane = threadIdx.x & 63;
    const int wave = threadIdx.x >> 6;
    const int m = lane & 15, quad = lane >> 4;
    const int row0 = blockIdx.x * 64 + wave * 16;

    f32x4 acc[3][8];
    #pragma unroll
    for (int mat = 0; mat < 3; mat++)
        #pragma unroll
        for (int ct = 0; ct < 8; ct++) acc[mat][ct] = (f32x4){0.f, 0.f, 0.f, 0.f};

    const unsigned short* arow = Xb + (size_t)(row0 + m) * FEAT + quad * 8;
    #pragma unroll
    for (int kc = 0; kc < 4; kc++) {
        bf16x8 a = *(const bf16x8*)(arow + kc * 32);
        #pragma unroll
        for (int mat = 0; mat < 3; mat++) {
            const unsigned short* wrow = Wb + mat * 16384 + (size_t)m * FEAT + kc * 32 + quad * 8;
            #pragma unroll
            for (int ct = 0; ct < 8; ct++) {
                bf16x8 b = *(const bf16x8*)(wrow + ct * 16 * FEAT);
                acc[mat][ct] = __builtin_amdgcn_mfma_f32_16x16x32_bf16(a, b, acc[mat][ct], 0, 0, 0);
            }
        }
    }

    unsigned short* outp[3] = {Q, K, V};
    const float* bias[3] = {bq, bk, bv};
    #pragma unroll
    for (int mat = 0; mat < 3; mat++) {
        #pragma unroll
        for (int ct = 0; ct < 8; ct++) {
            float bv_ = bias[mat][ct * 16 + m];
            #pragma unroll
            for (int reg = 0; reg < 4; reg++) {
                int row = row0 + quad * 4 + reg;
                if (row < N)
                    outp[mat][(size_t)row * FEAT + ct * 16 + m] = f2bf(acc[mat][ct][reg] + bv_);
            }
        }
    }
}

// ---- scores: one wave per SRC node. Q row in regs; per edge one random
//      coalesced K-row load; per-head dot via shfl_xor within 8-lane groups;
//      in-register segsum -> rsegsum (reciprocal). ----
__global__ __launch_bounds__(256) void scores_kernel(
    const int* __restrict__ offsets, const int* __restrict__ counts,
    const int* __restrict__ eid_src, const int* __restrict__ dst_sorted,
    const unsigned short* __restrict__ Q, const unsigned short* __restrict__ K,
    float* __restrict__ scores, float* __restrict__ rsegsum, int N)
{
    int node = blockIdx.x * 4 + (threadIdx.x >> 6);
    if (node >= N) return;
    int lane = threadIdx.x & 63;
    int start = offsets[node], deg = counts[node];
    unsigned q2 = *(const unsigned*)(Q + (size_t)node * FEAT + lane * 2);
    float qlo = bf2f_lo(q2), qhi = bf2f_hi(q2);
    float acc = 0.f;
    const int srcl = (lane & 7) * 8;   // lane holding head (lane&7)'s reduced value

    int j = 0;
    for (; j + 2 <= deg; j += 2) {
        int pos = start + j;
        int d0 = dst_sorted[pos], d1 = dst_sorted[pos + 1];
        unsigned k0 = *(const unsigned*)(K + (size_t)d0 * FEAT + lane * 2);
        unsigned k1 = *(const unsigned*)(K + (size_t)d1 * FEAT + lane * 2);
        float p0 = qlo * bf2f_lo(k0) + qhi * bf2f_hi(k0);
        float p1 = qlo * bf2f_lo(k1) + qhi * bf2f_hi(k1);
        p0 += __shfl_xor(p0, 1); p1 += __shfl_xor(p1, 1);
        p0 += __shfl_xor(p0, 2); p1 += __shfl_xor(p1, 2);
        p0 += __shfl_xor(p0, 4); p1 += __shfl_xor(p1, 4);
        float w0 = __expf(p0 * 0.25f);
        float w1 = __expf(p1 * 0.25f);
        acc += w0 + w1;
        float wo0 = __shfl(w0, srcl);
        float wo1 = __shfl(w1, srcl);
        if (lane < 8) {
            int e0 = eid_src[pos], e1 = eid_src[pos + 1];
            scores[(size_t)e0 * NHEAD + lane] = wo0;
            scores[(size_t)e1 * NHEAD + lane] = wo1;
        }
    }
    for (; j < deg; j++) {
        int pos = start + j;
        int d = dst_sorted[pos];
        unsigned k2 = *(const unsigned*)(K + (size_t)d * FEAT + lane * 2);
        float p = qlo * bf2f_lo(k2) + qhi * bf2f_hi(k2);
        p += __shfl_xor(p, 1);
        p += __shfl_xor(p, 2);
        p += __shfl_xor(p, 4);
        float wv = __expf(p * 0.25f);
        acc += wv;
        float wo = __shfl(wv, srcl);
        if (lane < 8) {
            int e = eid_src[pos];
            scores[(size_t)e * NHEAD + lane] = wo;
        }
    }
    float at = __shfl(acc, srcl);
    if (lane < 8) rsegsum[(size_t)node * NHEAD + lane] = 1.0f / at;
}

// ---- fill dest-CSR: src node + prenormalized weights, dest-sorted ----
__global__ __launch_bounds__(256) void fill_dst_kernel(
    const int* __restrict__ srcs, const int* __restrict__ dsts,
    int* __restrict__ cursor, const float* __restrict__ scores,
    const float* __restrict__ rsegsum, int* __restrict__ src_sorted,
    float* __restrict__ wnorm, int N, int E)
{
    int e = blockIdx.x * 256 + threadIdx.x;
    if (e >= E) return;
    int s = srcs[e], d = dsts[e];
    int pos = atomicAdd(cursor + N + d, 1) - E;
    src_sorted[pos] = s;
    const float4* sc = (const float4*)(scores + (size_t)e * NHEAD);
    const float4* rs = (const float4*)(rsegsum + (size_t)s * NHEAD);
    float4 s0 = sc[0], s1 = sc[1];
    float4 r0 = rs[0], r1 = rs[1];
    float4 o0 = {s0.x * r0.x, s0.y * r0.y, s0.z * r0.z, s0.w * r0.w};
    float4 o1 = {s1.x * r1.x, s1.y * r1.y, s1.z * r1.z, s1.w * r1.w};
    float4* wp = (float4*)(wnorm + (size_t)pos * NHEAD);
    wp[0] = o0; wp[1] = o1;
}

// ---- gather: one wave per dest node; streaming src/wnorm, 4x-unrolled
//      random V-row loads for MLP ----
__global__ __launch_bounds__(256) void gather_kernel(
    const int* __restrict__ offsets, const int* __restrict__ counts,
    const int* __restrict__ src_sorted, const float* __restrict__ wnorm,
    const unsigned short* __restrict__ V, unsigned short* __restrict__ agg,
    int N, int E)
{
    int node = blockIdx.x * 4 + (threadIdx.x >> 6);
    if (node >= N) return;
    int lane = threadIdx.x & 63;
    int h = lane >> 3;
    int start = offsets[node] - E, deg = counts[node];
    float ax = 0.f, ay = 0.f;
    int j = 0;
    for (; j + 4 <= deg; j += 4) {
        int p = start + j;
        int s0 = src_sorted[p], s1 = src_sorted[p + 1];
        int s2 = src_sorted[p + 2], s3 = src_sorted[p + 3];
        float w0 = wnorm[(size_t)(p + 0) * NHEAD + h];
        float w1 = wnorm[(size_t)(p + 1) * NHEAD + h];
        float w2 = wnorm[(size_t)(p + 2) * NHEAD + h];
        float w3 = wnorm[(size_t)(p + 3) * NHEAD + h];
        unsigned v0 = *(const unsigned*)(V + (size_t)s0 * FEAT + lane * 2);
        unsigned v1 = *(const unsigned*)(V + (size_t)s1 * FEAT + lane * 2);
        unsigned v2 = *(const unsigned*)(V + (size_t)s2 * FEAT + lane * 2);
        unsigned v3 = *(const unsigned*)(V + (size_t)s3 * FEAT + lane * 2);
        ax += w0 * bf2f_lo(v0) + w1 * bf2f_lo(v1) + w2 * bf2f_lo(v2) + w3 * bf2f_lo(v3);
        ay += w0 * bf2f_hi(v0) + w1 * bf2f_hi(v1) + w2 * bf2f_hi(v2) + w3 * bf2f_hi(v3);
    }
    for (; j < deg; j++) {
        int p = start + j;
        int s = src_sorted[p];
        float w = wnorm[(size_t)p * NHEAD + h];
        unsigned v = *(const unsigned*)(V + (size_t)s * FEAT + lane * 2);
        ax += w * bf2f_lo(v);
        ay += w * bf2f_hi(v);
    }
    unsigned o = (unsigned)f2bf(ax) | ((unsigned)f2bf(ay) << 16);
    *(unsigned*)(agg + (size_t)node * FEAT + lane * 2) = o;
}

// ---- out MFMA GEMM ----
__global__ __launch_bounds__(256) void out_mfma_kernel(
    const unsigned short* __restrict__ Ab, const unsigned short* __restrict__ Wob,
    const float* __restrict__ bo, float* __restrict__ out, int N)
{
    const int lane = threadIdx.x & 63;
    const int wave = threadIdx.x >> 6;
    const int m = lane & 15, quad = lane >> 4;
    const int row0 = blockIdx.x * 64 + wave * 16;

    f32x4 acc[8];
    #pragma unroll
    for (int ct = 0; ct < 8; ct++) acc[ct] = (f32x4){0.f, 0.f, 0.f, 0.f};

    const unsigned short* arow = Ab + (size_t)(row0 + m) * FEAT + quad * 8;
    #pragma unroll
    for (int kc = 0; kc < 4; kc++) {
        bf16x8 a = *(const bf16x8*)(arow + kc * 32);
        const unsigned short* wrow = Wob + (size_t)m * FEAT + kc * 32 + quad * 8;
        #pragma unroll
        for (int ct = 0; ct < 8; ct++) {
            bf16x8 b = *(const bf16x8*)(wrow + ct * 16 * FEAT);
            acc[ct] = __builtin_amdgcn_mfma_f32_16x16x32_bf16(a, b, acc[ct], 0, 0, 0);
        }
    }
    #pragma unroll
    for (int ct = 0; ct < 8; ct++) {
        float bv_ = bo[ct * 16 + m];
        #pragma unroll
        for (int reg = 0; reg < 4; reg++) {
            int row = row0 + quad * 4 + reg;
            if (row < N)
                out[(size_t)row * FEAT + ct * 16 + m] = acc[ct][reg] + bv_;
        }
    }
}

extern "C" void kernel_launch(void* const* d_in, const int* in_sizes, int n_in,
                              void* d_out, int out_size, void* d_ws, size_t ws_size,
                              hipStream_t stream) {
    const float* X  = (const float*)d_in[0];
    const int*   ei = (const int*)d_in[1];
    const float* Wq = (const float*)d_in[2];
    const float* bq = (const float*)d_in[3];
    const float* Wk = (const float*)d_in[4];
    const float* bk = (const float*)d_in[5];
    const float* Wv = (const float*)d_in[6];
    const float* bv = (const float*)d_in[7];
    const float* Wo = (const float*)d_in[8];
    const float* bo = (const float*)d_in[9];
    float* out = (float*)d_out;

    const int N = in_sizes[0] / FEAT;        // 50000
    const int E = in_sizes[1] / 2;           // 600000
    const int* srcs = ei;
    const int* dsts = ei + E;
    const size_t NF2 = (size_t)NPAD * FEAT * 2;   // bytes per bf16 node matrix

    // workspace layout (with aliasing):
    //   Xb (dead after qkv)    <- reused as Ab (gather output)
    //   Qb+Kb (dead after scores) <- reused as wnorm (19.2MB) + src_sorted
    char* w = (char*)d_ws;
    unsigned short* Xb = (unsigned short*)w;  w += NF2;       // also Ab
    unsigned short* Qb = (unsigned short*)w;  w += NF2;
    unsigned short* Kb = (unsigned short*)w;  w += NF2;
    unsigned short* Vb = (unsigned short*)w;  w += NF2;
    unsigned short* Wb = (unsigned short*)w;  w += (size_t)4 * 16384 * 2;
    float* scores      = (float*)w;           w += (size_t)E * NHEAD * 4;
    float* rsegsum     = (float*)w;           w += (size_t)N * NHEAD * 4;
    int* counts        = (int*)w;             w += (size_t)2 * N * 4;
    int* offsets       = (int*)w;             w += (size_t)2 * N * 4;
    int* cursor        = (int*)w;             w += (size_t)2 * N * 4;
    int* blocksums     = (int*)w;             w += 512 * 4;
    int* blockoffs     = (int*)w;             w += 512 * 4;
    int* eid_src       = (int*)w;             w += (size_t)E * 4;
    int* dst_sorted    = (int*)w;             w += (size_t)E * 4;

    unsigned short* Ab = Xb;                          // after qkv
    float* wnorm       = (float*)Qb;                  // after scores (19.2MB < 25.6MB)
    int*   src_sorted  = (int*)((char*)Qb + (size_t)E * NHEAD * 4);

    hipMemsetAsync(counts, 0, (size_t)2 * N * sizeof(int), stream);

    convert_w_kernel<<<(4 * 2048 + 255) / 256, 256, 0, stream>>>(Wq, Wk, Wv, Wo, Wb);

    int x8 = N * FEAT / 8;
    convert_x_kernel<<<(x8 + 255) / 256, 256, 0, stream>>>(X, Xb, x8);

    int e_blocks = (E + 255) / 256;
    hist2_kernel<<<e_blocks, 256, 0, stream>>>(srcs, dsts, counts, N, E);

    int NT = 2 * N;
    int NB2 = (NT + 255) / 256;   // 391 <= 512
    scan1_kernel<<<NB2, 256, 0, stream>>>(counts, offsets, blocksums, NT);
    scan2_kernel<<<1, 512, 0, stream>>>(blocksums, blockoffs, NB2);
    scan3_kernel<<<NB2, 256, 0, stream>>>(offsets, blockoffs, cursor, NT);

    fill_src_kernel<<<e_blocks, 256, 0, stream>>>(srcs, dsts, cursor, eid_src, dst_sorted, E);

    int row_blocks = NPAD / 64;
    qkv_mfma_kernel<<<row_blocks, 256, 0, stream>>>(Xb, Wb, bq, bk, bv, Qb, Kb, Vb, N);

    int node_blocks = (N + 3) / 4;
    scores_kernel<<<node_blocks, 256, 0, stream>>>(
        offsets, counts, eid_src, dst_sorted, Qb, Kb, scores, rsegsum, N);

    fill_dst_kernel<<<e_blocks, 256, 0, stream>>>(
        srcs, dsts, cursor, scores, rsegsum, src_sorted, wnorm, N, E);

    gather_kernel<<<node_blocks, 256, 0, stream>>>(
        offsets + N, counts + N, src_sorted, wnorm, Vb, Ab, N, E);

    out_mfma_kernel<<<row_blocks, 256, 0, stream>>>(Ab, Wb + 3 * 16384, bo, out, N);
}

// Round 5
// 382.534 us; speedup vs baseline: 1.0816x; 1.0816x over previous
//
#include <hip/hip_runtime.h>
#include <hip/hip_bf16.h>

// GAT-style graph attention. N=50000, E=600000, FEAT=128, H=8, D=16.
// R5: MFMA GEMMs restructured: B fragments persistent in registers
//     (wave owns a 32-col strip), grid-stride over 16-row tiles -> no
//     per-tile B reload (R4 was latency-bound on serialized B loads).
//     fill_dst deleted: fill_src builds both CSRs; scores scatters raw
//     exp(w) into dest order; gather normalizes via rsegsum[src].

#define FEAT 128
#define NHEAD 8
#define NPAD 50048   // N rounded up to multiple of 64

typedef __attribute__((ext_vector_type(8))) short bf16x8;
typedef __attribute__((ext_vector_type(4))) float f32x4;

__device__ __forceinline__ unsigned short f2bf(float f) {
    unsigned u = __float_as_uint(f);
    u += 0x7fffu + ((u >> 16) & 1u);
    return (unsigned short)(u >> 16);
}
__device__ __forceinline__ float bf2f_lo(unsigned u) { return __uint_as_float(u << 16); }
__device__ __forceinline__ float bf2f_hi(unsigned u) { return __uint_as_float(u & 0xffff0000u); }

// ---- convert X to bf16, 8 elems/thread ----
__global__ __launch_bounds__(256) void convert_x_kernel(
    const float* __restrict__ X, unsigned short* __restrict__ Xb, int total8)
{
    int i = blockIdx.x * 256 + threadIdx.x;
    if (i >= total8) return;
    const float4* xp = (const float4*)X + (size_t)i * 2;
    float4 x0 = xp[0], x1 = xp[1];
    uint4 o;
    o.x = (unsigned)f2bf(x0.x) | ((unsigned)f2bf(x0.y) << 16);
    o.y = (unsigned)f2bf(x0.z) | ((unsigned)f2bf(x0.w) << 16);
    o.z = (unsigned)f2bf(x1.x) | ((unsigned)f2bf(x1.y) << 16);
    o.w = (unsigned)f2bf(x1.z) | ((unsigned)f2bf(x1.w) << 16);
    ((uint4*)Xb)[i] = o;
}

// ---- convert 4 weight matrices to bf16 ----
__global__ __launch_bounds__(256) void convert_w_kernel(
    const float* __restrict__ Wq, const float* __restrict__ Wk,
    const float* __restrict__ Wv, const float* __restrict__ Wo,
    unsigned short* __restrict__ Wb)
{
    int i = blockIdx.x * 256 + threadIdx.x;
    if (i >= 4 * 2048) return;
    int mat = i >> 11, idx = i & 2047;
    const float* W = (mat == 0) ? Wq : (mat == 1) ? Wk : (mat == 2) ? Wv : Wo;
    const float4* xp = (const float4*)W + (size_t)idx * 2;
    float4 x0 = xp[0], x1 = xp[1];
    uint4 o;
    o.x = (unsigned)f2bf(x0.x) | ((unsigned)f2bf(x0.y) << 16);
    o.y = (unsigned)f2bf(x0.z) | ((unsigned)f2bf(x0.w) << 16);
    o.z = (unsigned)f2bf(x1.x) | ((unsigned)f2bf(x1.y) << 16);
    o.w = (unsigned)f2bf(x1.z) | ((unsigned)f2bf(x1.w) << 16);
    ((uint4*)(Wb + (size_t)mat * 16384))[idx] = o;
}

// ---- combined histogram: counts[s] and counts[N+d] ----
__global__ __launch_bounds__(256) void hist2_kernel(
    const int* __restrict__ srcs, const int* __restrict__ dsts,
    int* __restrict__ counts, int N, int E)
{
    int e = blockIdx.x * 256 + threadIdx.x;
    if (e < E) {
        atomicAdd(counts + srcs[e], 1);
        atomicAdd(counts + N + dsts[e], 1);
    }
}

// ---- scan over concatenated [src counts | dest counts] (2N elems) ----
__global__ __launch_bounds__(256) void scan1_kernel(
    const int* __restrict__ counts, int* __restrict__ offsets,
    int* __restrict__ blocksums, int NT)
{
    __shared__ int buf[256];
    int t = threadIdx.x, i = blockIdx.x * 256 + t;
    int v = (i < NT) ? counts[i] : 0;
    buf[t] = v; __syncthreads();
    int x = v;
    #pragma unroll
    for (int off = 1; off < 256; off <<= 1) {
        int y = (t >= off) ? buf[t - off] : 0;
        __syncthreads();
        x += y; buf[t] = x;
        __syncthreads();
    }
    if (i < NT) offsets[i] = x - v;
    if (t == 255) blocksums[blockIdx.x] = x;
}

__global__ __launch_bounds__(512) void scan2_kernel(
    int* __restrict__ blocksums, int* __restrict__ blockoffs, int NB)
{
    __shared__ int buf[512];
    int t = threadIdx.x;
    int v = (t < NB) ? blocksums[t] : 0;
    buf[t] = v; __syncthreads();
    int x = v;
    #pragma unroll
    for (int off = 1; off < 512; off <<= 1) {
        int y = (t >= off) ? buf[t - off] : 0;
        __syncthreads();
        x += y; buf[t] = x;
        __syncthreads();
    }
    if (t < NB) blockoffs[t] = x - v;
}

__global__ __launch_bounds__(256) void scan3_kernel(
    int* __restrict__ offsets, const int* __restrict__ blockoffs,
    int* __restrict__ cursor, int NT)
{
    int i = blockIdx.x * 256 + threadIdx.x;
    if (i < NT) {
        int o = offsets[i] + blockoffs[blockIdx.x];
        offsets[i] = o;
        cursor[i] = o;
    }
}

// ---- fill BOTH CSRs in one pass ----
// src order: dst_sorted[ps], posd_sorted[ps] (edge's slot in dest-CSR)
// dest order: src_sorted[pd]
__global__ __launch_bounds__(256) void fill_src_kernel(
    const int* __restrict__ srcs, const int* __restrict__ dsts,
    int* __restrict__ cursor, int* __restrict__ dst_sorted,
    int* __restrict__ posd_sorted, int* __restrict__ src_sorted, int N, int E)
{
    int e = blockIdx.x * 256 + threadIdx.x;
    if (e >= E) return;
    int s = srcs[e], d = dsts[e];
    int ps = atomicAdd(cursor + s, 1);
    int pd = atomicAdd(cursor + N + d, 1) - E;
    dst_sorted[ps] = d;
    posd_sorted[ps] = pd;
    src_sorted[pd] = s;
}

// ---- QKV MFMA GEMM v2: wave owns 32-col strip, B frags persistent in regs,
//      grid-stride over 16-row tiles (4 A-loads + 24 MFMAs per tile) ----
__global__ __launch_bounds__(256) void qkv_mfma_kernel(
    const unsigned short* __restrict__ Xb, const unsigned short* __restrict__ Wb,
    const float* __restrict__ bq, const float* __restrict__ bk, const float* __restrict__ bv,
    unsigned short* __restrict__ Q, unsigned short* __restrict__ K,
    unsigned short* __restrict__ V, int N, int numTiles)
{
    const int lane = threadIdx.x & 63;
    const int wave = threadIdx.x >> 6;
    const int m = lane & 15, quad = lane >> 4;
    const int colbase = wave * 32;

    bf16x8 bfr[3][2][4];
    #pragma unroll
    for (int mat = 0; mat < 3; mat++)
        #pragma unroll
        for (int ctl = 0; ctl < 2; ctl++) {
            const unsigned short* wrow =
                Wb + mat * 16384 + (size_t)(colbase + ctl * 16 + m) * FEAT + quad * 8;
            #pragma unroll
            for (int kc = 0; kc < 4; kc++)
                bfr[mat][ctl][kc] = *(const bf16x8*)(wrow + kc * 32);
        }

    const float* bias_p[3] = {bq, bk, bv};
    float bias[3][2];
    #pragma unroll
    for (int mat = 0; mat < 3; mat++)
        #pragma unroll
        for (int ctl = 0; ctl < 2; ctl++)
            bias[mat][ctl] = bias_p[mat][colbase + ctl * 16 + m];

    unsigned short* outp[3] = {Q, K, V};

    for (int tile = blockIdx.x; tile < numTiles; tile += gridDim.x) {
        const int row0 = tile * 16;
        const unsigned short* arow = Xb + (size_t)(row0 + m) * FEAT + quad * 8;
        bf16x8 a[4];
        #pragma unroll
        for (int kc = 0; kc < 4; kc++) a[kc] = *(const bf16x8*)(arow + kc * 32);
        f32x4 acc[3][2];
        #pragma unroll
        for (int mat = 0; mat < 3; mat++)
            #pragma unroll
            for (int ctl = 0; ctl < 2; ctl++) acc[mat][ctl] = (f32x4){0.f, 0.f, 0.f, 0.f};
        #pragma unroll
        for (int kc = 0; kc < 4; kc++)
            #pragma unroll
            for (int mat = 0; mat < 3; mat++)
                #pragma unroll
                for (int ctl = 0; ctl < 2; ctl++)
                    acc[mat][ctl] = __builtin_amdgcn_mfma_f32_16x16x32_bf16(
                        a[kc], bfr[mat][ctl][kc], acc[mat][ctl], 0, 0, 0);
        #pragma unroll
        for (int mat = 0; mat < 3; mat++)
            #pragma unroll
            for (int ctl = 0; ctl < 2; ctl++)
                #pragma unroll
                for (int reg = 0; reg < 4; reg++) {
                    int row = row0 + quad * 4 + reg;
                    if (row < N)
                        outp[mat][(size_t)row * FEAT + colbase + ctl * 16 + m] =
                            f2bf(acc[mat][ctl][reg] + bias[mat][ctl]);
                }
    }
}

// ---- scores: one wave per SRC node; Q row in regs; per-edge random K-row
//      load; shfl-reduce; writes RAW exp(w) scattered into dest-CSR order;
//      rsegsum = 1/sum in src order ----
__global__ __launch_bounds__(256) void scores_kernel(
    const int* __restrict__ offsets, const int* __restrict__ counts,
    const int* __restrict__ posd_sorted, const int* __restrict__ dst_sorted,
    const unsigned short* __restrict__ Q, const unsigned short* __restrict__ K,
    float* __restrict__ wraw, float* __restrict__ rsegsum, int N)
{
    int node = blockIdx.x * 4 + (threadIdx.x >> 6);
    if (node >= N) return;
    int lane = threadIdx.x & 63;
    int start = offsets[node], deg = counts[node];
    unsigned q2 = *(const unsigned*)(Q + (size_t)node * FEAT + lane * 2);
    float qlo = bf2f_lo(q2), qhi = bf2f_hi(q2);
    float acc = 0.f;
    const int srcl = (lane & 7) * 8;

    int j = 0;
    for (; j + 2 <= deg; j += 2) {
        int pos = start + j;
        int d0 = dst_sorted[pos], d1 = dst_sorted[pos + 1];
        unsigned k0 = *(const unsigned*)(K + (size_t)d0 * FEAT + lane * 2);
        unsigned k1 = *(const unsigned*)(K + (size_t)d1 * FEAT + lane * 2);
        float p0 = qlo * bf2f_lo(k0) + qhi * bf2f_hi(k0);
        float p1 = qlo * bf2f_lo(k1) + qhi * bf2f_hi(k1);
        p0 += __shfl_xor(p0, 1); p1 += __shfl_xor(p1, 1);
        p0 += __shfl_xor(p0, 2); p1 += __shfl_xor(p1, 2);
        p0 += __shfl_xor(p0, 4); p1 += __shfl_xor(p1, 4);
        float w0 = __expf(p0 * 0.25f);
        float w1 = __expf(p1 * 0.25f);
        acc += w0 + w1;
        float wo0 = __shfl(w0, srcl);
        float wo1 = __shfl(w1, srcl);
        if (lane < 8) {
            int pd0 = posd_sorted[pos], pd1 = posd_sorted[pos + 1];
            wraw[(size_t)pd0 * NHEAD + lane] = wo0;
            wraw[(size_t)pd1 * NHEAD + lane] = wo1;
        }
    }
    for (; j < deg; j++) {
        int pos = start + j;
        int d = dst_sorted[pos];
        unsigned k2 = *(const unsigned*)(K + (size_t)d * FEAT + lane * 2);
        float p = qlo * bf2f_lo(k2) + qhi * bf2f_hi(k2);
        p += __shfl_xor(p, 1);
        p += __shfl_xor(p, 2);
        p += __shfl_xor(p, 4);
        float wv = __expf(p * 0.25f);
        acc += wv;
        float wo = __shfl(wv, srcl);
        if (lane < 8) {
            int pd = posd_sorted[pos];
            wraw[(size_t)pd * NHEAD + lane] = wo;
        }
    }
    float at = __shfl(acc, srcl);
    if (lane < 8) rsegsum[(size_t)node * NHEAD + lane] = 1.0f / at;
}

// ---- gather: one wave per dest node; streaming src_sorted/wraw,
//      rsegsum[src] normalization, 4x-unrolled random V-row loads ----
__global__ __launch_bounds__(256) void gather_kernel(
    const int* __restrict__ offsets, const int* __restrict__ counts,
    const int* __restrict__ src_sorted, const float* __restrict__ wraw,
    const float* __restrict__ rsegsum, const unsigned short* __restrict__ V,
    unsigned short* __restrict__ agg, int N, int E)
{
    int node = blockIdx.x * 4 + (threadIdx.x >> 6);
    if (node >= N) return;
    int lane = threadIdx.x & 63;
    int h = lane >> 3;
    int start = offsets[node] - E, deg = counts[node];
    float ax = 0.f, ay = 0.f;
    int j = 0;
    for (; j + 4 <= deg; j += 4) {
        int p = start + j;
        int s0 = src_sorted[p], s1 = src_sorted[p + 1];
        int s2 = src_sorted[p + 2], s3 = src_sorted[p + 3];
        float w0 = wraw[(size_t)(p + 0) * NHEAD + h] * rsegsum[(size_t)s0 * NHEAD + h];
        float w1 = wraw[(size_t)(p + 1) * NHEAD + h] * rsegsum[(size_t)s1 * NHEAD + h];
        float w2 = wraw[(size_t)(p + 2) * NHEAD + h] * rsegsum[(size_t)s2 * NHEAD + h];
        float w3 = wraw[(size_t)(p + 3) * NHEAD + h] * rsegsum[(size_t)s3 * NHEAD + h];
        unsigned v0 = *(const unsigned*)(V + (size_t)s0 * FEAT + lane * 2);
        unsigned v1 = *(const unsigned*)(V + (size_t)s1 * FEAT + lane * 2);
        unsigned v2 = *(const unsigned*)(V + (size_t)s2 * FEAT + lane * 2);
        unsigned v3 = *(const unsigned*)(V + (size_t)s3 * FEAT + lane * 2);
        ax += w0 * bf2f_lo(v0) + w1 * bf2f_lo(v1) + w2 * bf2f_lo(v2) + w3 * bf2f_lo(v3);
        ay += w0 * bf2f_hi(v0) + w1 * bf2f_hi(v1) + w2 * bf2f_hi(v2) + w3 * bf2f_hi(v3);
    }
    for (; j < deg; j++) {
        int p = start + j;
        int s = src_sorted[p];
        float w = wraw[(size_t)p * NHEAD + h] * rsegsum[(size_t)s * NHEAD + h];
        unsigned v = *(const unsigned*)(V + (size_t)s * FEAT + lane * 2);
        ax += w * bf2f_lo(v);
        ay += w * bf2f_hi(v);
    }
    unsigned o = (unsigned)f2bf(ax) | ((unsigned)f2bf(ay) << 16);
    *(unsigned*)(agg + (size_t)node * FEAT + lane * 2) = o;
}

// ---- out MFMA GEMM v2: same persistent-B structure, 1 matrix, f32 out ----
__global__ __launch_bounds__(256) void out_mfma_kernel(
    const unsigned short* __restrict__ Ab, const unsigned short* __restrict__ Wob,
    const float* __restrict__ bo, float* __restrict__ out, int N, int numTiles)
{
    const int lane = threadIdx.x & 63;
    const int wave = threadIdx.x >> 6;
    const int m = lane & 15, quad = lane >> 4;
    const int colbase = wave * 32;

    bf16x8 bfr[2][4];
    #pragma unroll
    for (int ctl = 0; ctl < 2; ctl++) {
        const unsigned short* wrow = Wob + (size_t)(colbase + ctl * 16 + m) * FEAT + quad * 8;
        #pragma unroll
        for (int kc = 0; kc < 4; kc++)
            bfr[ctl][kc] = *(const bf16x8*)(wrow + kc * 32);
    }
    float bias[2];
    #pragma unroll
    for (int ctl = 0; ctl < 2; ctl++) bias[ctl] = bo[colbase + ctl * 16 + m];

    for (int tile = blockIdx.x; tile < numTiles; tile += gridDim.x) {
        const int row0 = tile * 16;
        const unsigned short* arow = Ab + (size_t)(row0 + m) * FEAT + quad * 8;
        bf16x8 a[4];
        #pragma unroll
        for (int kc = 0; kc < 4; kc++) a[kc] = *(const bf16x8*)(arow + kc * 32);
        f32x4 acc[2];
        #pragma unroll
        for (int ctl = 0; ctl < 2; ctl++) acc[ctl] = (f32x4){0.f, 0.f, 0.f, 0.f};
        #pragma unroll
        for (int kc = 0; kc < 4; kc++)
            #pragma unroll
            for (int ctl = 0; ctl < 2; ctl++)
                acc[ctl] = __builtin_amdgcn_mfma_f32_16x16x32_bf16(
                    a[kc], bfr[ctl][kc], acc[ctl], 0, 0, 0);
        #pragma unroll
        for (int ctl = 0; ctl < 2; ctl++)
            #pragma unroll
            for (int reg = 0; reg < 4; reg++) {
                int row = row0 + quad * 4 + reg;
                if (row < N)
                    out[(size_t)row * FEAT + colbase + ctl * 16 + m] = acc[ctl][reg] + bias[ctl];
            }
    }
}

extern "C" void kernel_launch(void* const* d_in, const int* in_sizes, int n_in,
                              void* d_out, int out_size, void* d_ws, size_t ws_size,
                              hipStream_t stream) {
    const float* X  = (const float*)d_in[0];
    const int*   ei = (const int*)d_in[1];
    const float* Wq = (const float*)d_in[2];
    const float* bq = (const float*)d_in[3];
    const float* Wk = (const float*)d_in[4];
    const float* bk = (const float*)d_in[5];
    const float* Wv = (const float*)d_in[6];
    const float* bv = (const float*)d_in[7];
    const float* Wo = (const float*)d_in[8];
    const float* bo = (const float*)d_in[9];
    float* out = (float*)d_out;

    const int N = in_sizes[0] / FEAT;        // 50000
    const int E = in_sizes[1] / 2;           // 600000
    const int* srcs = ei;
    const int* dsts = ei + E;
    const size_t NF2 = (size_t)NPAD * FEAT * 2;

    char* w = (char*)d_ws;
    unsigned short* Xb = (unsigned short*)w;  w += NF2;       // also Ab (after qkv)
    unsigned short* Qb = (unsigned short*)w;  w += NF2;
    unsigned short* Kb = (unsigned short*)w;  w += NF2;
    unsigned short* Vb = (unsigned short*)w;  w += NF2;
    unsigned short* Wb = (unsigned short*)w;  w += (size_t)4 * 16384 * 2;
    float* wraw        = (float*)w;           w += (size_t)E * NHEAD * 4;
    float* rsegsum     = (float*)w;           w += (size_t)N * NHEAD * 4;
    int* counts        = (int*)w;             w += (size_t)2 * N * 4;
    int* offsets       = (int*)w;             w += (size_t)2 * N * 4;
    int* cursor        = (int*)w;             w += (size_t)2 * N * 4;
    int* blocksums     = (int*)w;             w += 512 * 4;
    int* blockoffs     = (int*)w;             w += 512 * 4;
    int* dst_sorted    = (int*)w;             w += (size_t)E * 4;
    int* posd_sorted   = (int*)w;             w += (size_t)E * 4;
    int* src_sorted    = (int*)w;             w += (size_t)E * 4;

    unsigned short* Ab = Xb;   // Xb dead after qkv

    hipMemsetAsync(counts, 0, (size_t)2 * N * sizeof(int), stream);

    convert_w_kernel<<<(4 * 2048 + 255) / 256, 256, 0, stream>>>(Wq, Wk, Wv, Wo, Wb);

    int x8 = N * FEAT / 8;
    convert_x_kernel<<<(x8 + 255) / 256, 256, 0, stream>>>(X, Xb, x8);

    int e_blocks = (E + 255) / 256;
    hist2_kernel<<<e_blocks, 256, 0, stream>>>(srcs, dsts, counts, N, E);

    int NT = 2 * N;
    int NB2 = (NT + 255) / 256;
    scan1_kernel<<<NB2, 256, 0, stream>>>(counts, offsets, blocksums, NT);
    scan2_kernel<<<1, 512, 0, stream>>>(blocksums, blockoffs, NB2);
    scan3_kernel<<<NB2, 256, 0, stream>>>(offsets, blockoffs, cursor, NT);

    fill_src_kernel<<<e_blocks, 256, 0, stream>>>(
        srcs, dsts, cursor, dst_sorted, posd_sorted, src_sorted, N, E);

    int numTiles = NPAD / 16;   // 3128
    qkv_mfma_kernel<<<782, 256, 0, stream>>>(Xb, Wb, bq, bk, bv, Qb, Kb, Vb, N, numTiles);

    int node_blocks = (N + 3) / 4;
    scores_kernel<<<node_blocks, 256, 0, stream>>>(
        offsets, counts, posd_sorted, dst_sorted, Qb, Kb, wraw, rsegsum, N);

    gather_kernel<<<node_blocks, 256, 0, stream>>>(
        offsets + N, counts + N, src_sorted, wraw, rsegsum, Vb, Ab, N, E);

    out_mfma_kernel<<<782, 256, 0, stream>>>(Ab, Wb + 3 * 16384, bo, out, N, numTiles);
}